// Round 1
// baseline (482.115 us; speedup 1.0000x reference)
//
#include <hip/hip_runtime.h>
#include <hip/hip_bf16.h>

#define DEV __device__ __forceinline__

typedef __attribute__((ext_vector_type(8))) short bf16x8;
typedef __attribute__((ext_vector_type(4))) short s16x4;
typedef __attribute__((ext_vector_type(4))) float f32x4;
typedef unsigned int u32;

DEV short f2bf(float f) {
  union { float f; u32 u; } x; x.f = f;
  u32 r = x.u + 0x7fffu + ((x.u >> 16) & 1u);   // RNE
  return (short)(r >> 16);
}

DEV void gload_lds16(const void* g, void* l) {
  __builtin_amdgcn_global_load_lds(
      (const __attribute__((address_space(1))) u32*)g,
      (__attribute__((address_space(3))) u32*)l, 16, 0, 0);
}

// ---------- weight fp32 (K x N) -> bf16 transposed (N x K) ----------
__global__ __launch_bounds__(256) void wconv_t(const float* __restrict__ W,
                                               short* __restrict__ Wt) {
  __shared__ short tile[64][65];
  int k0 = blockIdx.x * 64, n0 = blockIdx.y * 64;
  int t = threadIdx.x;
  int r = t >> 2, c = (t & 3) * 16;
  const float* src = W + (size_t)(k0 + r) * 1024 + n0 + c;
#pragma unroll
  for (int i = 0; i < 16; i += 4) {
    float4 f = *(const float4*)(src + i);
    tile[r][c + i + 0] = f2bf(f.x);
    tile[r][c + i + 1] = f2bf(f.y);
    tile[r][c + i + 2] = f2bf(f.z);
    tile[r][c + i + 3] = f2bf(f.w);
  }
  __syncthreads();
  bf16x8 v0, v1;
#pragma unroll
  for (int i = 0; i < 8; ++i) v0[i] = tile[c + i][r];
#pragma unroll
  for (int i = 0; i < 8; ++i) v1[i] = tile[c + 8 + i][r];
  short* dst = Wt + (size_t)(n0 + r) * 1024 + k0 + c;
  *(bf16x8*)(dst) = v0;
  *(bf16x8*)(dst + 8) = v1;
}

// ---------- vh (B,H,M,D) -> vht (B,H,D,M), bf16 ----------
__global__ __launch_bounds__(256) void vtrans(const short* __restrict__ vh,
                                              short* __restrict__ vht) {
  __shared__ short tile[64][65];
  int m0 = blockIdx.x * 64;
  int bh = blockIdx.y;
  int t = threadIdx.x;
  int r = t >> 2, c = (t & 3) * 16;
  const short* src = vh + ((size_t)bh * 1024 + m0 + r) * 64 + c;
  bf16x8 a0 = *(const bf16x8*)(src);
  bf16x8 a1 = *(const bf16x8*)(src + 8);
#pragma unroll
  for (int i = 0; i < 8; ++i) tile[r][c + i] = a0[i];
#pragma unroll
  for (int i = 0; i < 8; ++i) tile[r][c + 8 + i] = a1[i];
  __syncthreads();
  bf16x8 v0, v1;
#pragma unroll
  for (int i = 0; i < 8; ++i) v0[i] = tile[c + i][r];
#pragma unroll
  for (int i = 0; i < 8; ++i) v1[i] = tile[c + 8 + i][r];
  short* dst = vht + ((size_t)bh * 64 + r) * 1024 + m0 + c;
  *(bf16x8*)dst = v0;
  *(bf16x8*)(dst + 8) = v1;
}

// ---------- QKV projection GEMM: A(8192x1024 f32) @ Wt^T -> (B,H,N,64) bf16 ----------
__global__ __launch_bounds__(256, 2) void gemm_qkv(
    const float* __restrict__ Aq, const float* __restrict__ Ak, const float* __restrict__ Av,
    const short* __restrict__ Wqt, const short* __restrict__ Wkt, const short* __restrict__ Wvt,
    short* __restrict__ qh, short* __restrict__ kh, short* __restrict__ vh) {
  const float* A; const short* Wt; short* Ch;
  if (blockIdx.z == 0)      { A = Aq; Wt = Wqt; Ch = qh; }
  else if (blockIdx.z == 1) { A = Ak; Wt = Wkt; Ch = kh; }
  else                      { A = Av; Wt = Wvt; Ch = vh; }

  __shared__ __align__(16) short As[128 * 64];  // [m][k]
  __shared__ __align__(16) short Bs[128 * 64];  // [n][k]

  int tid = threadIdx.x;
  int lane = tid & 63, w = tid >> 6;
  int wm = w >> 1, wn = w & 1;
  int lr = lane & 15, lg = lane >> 4;
  int bm = blockIdx.x * 128, bn = blockIdx.y * 128;

  const f32x4 fz = {0.f, 0.f, 0.f, 0.f};
  f32x4 acc[4][4];
#pragma unroll
  for (int i = 0; i < 4; ++i)
#pragma unroll
    for (int j = 0; j < 4; ++j) acc[i][j] = fz;

  int arow = tid >> 1, ahalf = tid & 1;
  const float* abase = A + (size_t)(bm + arow) * 1024 + ahalf * 32;
  short* adst = &As[arow * 64 + ahalf * 32];
  const char* wbase = (const char*)Wt;

  for (int kt = 0; kt < 1024; kt += 64) {
    // A: fp32 -> bf16 register-staged
#pragma unroll
    for (int i = 0; i < 8; ++i) {
      float4 f = *(const float4*)(abase + kt + i * 4);
      s16x4 s;
      s[0] = f2bf(f.x); s[1] = f2bf(f.y); s[2] = f2bf(f.z); s[3] = f2bf(f.w);
      *(s16x4*)(adst + i * 4) = s;
    }
    // B: async global->LDS, 16B/lane, linear dest
#pragma unroll
    for (int i = 0; i < 4; ++i) {
      int c = w * 4 + i;
      const char* src = wbase + (size_t)(bn + c * 8 + (lane >> 3)) * 2048 + kt * 2 + (lane & 7) * 16;
      gload_lds16(src, (char*)Bs + c * 1024);
    }
    __syncthreads();
#pragma unroll
    for (int ks = 0; ks < 2; ++ks) {
      bf16x8 af[4], bfr[4];
#pragma unroll
      for (int mi = 0; mi < 4; ++mi)
        af[mi] = *(const bf16x8*)&As[(wm * 64 + mi * 16 + lr) * 64 + ks * 32 + lg * 8];
#pragma unroll
      for (int ni = 0; ni < 4; ++ni)
        bfr[ni] = *(const bf16x8*)&Bs[(wn * 64 + ni * 16 + lr) * 64 + ks * 32 + lg * 8];
#pragma unroll
      for (int mi = 0; mi < 4; ++mi)
#pragma unroll
        for (int ni = 0; ni < 4; ++ni)
          acc[mi][ni] = __builtin_amdgcn_mfma_f32_16x16x32_bf16(af[mi], bfr[ni], acc[mi][ni], 0, 0, 0);
    }
    __syncthreads();
  }
  // epilogue: write (B,H,N,64)
#pragma unroll
  for (int mi = 0; mi < 4; ++mi)
#pragma unroll
    for (int ni = 0; ni < 4; ++ni) {
      int ccol = bn + wn * 64 + ni * 16 + lr;
      int h = ccol >> 6, d = ccol & 63;
#pragma unroll
      for (int j = 0; j < 4; ++j) {
        int r = bm + wm * 64 + mi * 16 + lg * 4 + j;
        int bb = r >> 10, n = r & 1023;
        Ch[(((size_t)bb * 16 + h) * 1024 + n) * 64 + d] = f2bf(acc[mi][ni][j]);
      }
    }
}

// ---------- flash attention: per (b,h) head, 128-query tile ----------
__global__ __launch_bounds__(256, 2) void attn(
    const short* __restrict__ qh, const short* __restrict__ kh, const short* __restrict__ vht,
    const int* __restrict__ mask, const int* __restrict__ tmask, short* __restrict__ x) {
  __shared__ __align__(16) short Ks[64 * 64];   // [key][d]
  __shared__ __align__(16) short Vs[64 * 64];   // [d][key]
  __shared__ __align__(16) short Ps[128 * 64];  // [qrow][key]

  int qt = blockIdx.x, bh = blockIdx.y;
  int b = bh >> 4, h = bh & 15;
  int tid = threadIdx.x, lane = tid & 63, w = tid >> 6;
  int lr = lane & 15, lg = lane >> 4;

  // Q fragments held in registers for the whole kernel
  bf16x8 qa[2][2];
  {
    const short* qb = qh + ((size_t)bh * 1024 + qt * 128 + w * 32) * 64;
#pragma unroll
    for (int mi = 0; mi < 2; ++mi)
#pragma unroll
      for (int ks = 0; ks < 2; ++ks)
        qa[mi][ks] = *(const bf16x8*)(qb + (mi * 16 + lr) * 64 + ks * 32 + lg * 8);
  }

  const f32x4 fz = {0.f, 0.f, 0.f, 0.f};
  f32x4 o[2][4];
  float mrun[2][4], lrun[2][4];
#pragma unroll
  for (int mi = 0; mi < 2; ++mi)
#pragma unroll
    for (int j = 0; j < 4; ++j) { mrun[mi][j] = -1e9f; lrun[mi][j] = 0.f; }
#pragma unroll
  for (int mi = 0; mi < 2; ++mi)
#pragma unroll
    for (int nd = 0; nd < 4; ++nd) o[mi][nd] = fz;

  const char* kbase = (const char*)(kh + (size_t)bh * 1024 * 64);
  const char* vbase = (const char*)(vht + (size_t)bh * 64 * 1024);
  const int* mrow = mask + b * 1024;
  const int* tbase = tmask + (size_t)b * 1024 * 1024;

  for (int t = 0; t < 16; ++t) {
    int kv0 = t * 64;
    // stage K[key][d] and V^T[d][key] tiles
#pragma unroll
    for (int i = 0; i < 2; ++i) {
      int c = w * 2 + i;
      const char* ksrc = kbase + (size_t)(kv0 + c * 8 + (lane >> 3)) * 128 + (lane & 7) * 16;
      gload_lds16(ksrc, (char*)Ks + c * 1024);
      const char* vsrc = vbase + (size_t)(c * 8 + (lane >> 3)) * 2048 + kv0 * 2 + (lane & 7) * 16;
      gload_lds16(vsrc, (char*)Vs + c * 1024);
    }
    __syncthreads();

    // S = Q K^T
    f32x4 s[2][4];
#pragma unroll
    for (int mi = 0; mi < 2; ++mi)
#pragma unroll
      for (int ni = 0; ni < 4; ++ni) s[mi][ni] = fz;
#pragma unroll
    for (int ks = 0; ks < 2; ++ks) {
      bf16x8 kb[4];
#pragma unroll
      for (int ni = 0; ni < 4; ++ni)
        kb[ni] = *(const bf16x8*)&Ks[(ni * 16 + lr) * 64 + ks * 32 + lg * 8];
#pragma unroll
      for (int mi = 0; mi < 2; ++mi)
#pragma unroll
        for (int ni = 0; ni < 4; ++ni)
          s[mi][ni] = __builtin_amdgcn_mfma_f32_16x16x32_bf16(qa[mi][ks], kb[ni], s[mi][ni], 0, 0, 0);
    }

    // masks + online softmax (per lane: 8 query rows, 16-lane groups own 16 keys/frag)
    int km[4];
#pragma unroll
    for (int ni = 0; ni < 4; ++ni) km[ni] = mrow[kv0 + ni * 16 + lr];

#pragma unroll
    for (int mi = 0; mi < 2; ++mi) {
#pragma unroll
      for (int j = 0; j < 4; ++j) {
        int qg = qt * 128 + w * 32 + mi * 16 + lg * 4 + j;
        const int* trow = tbase + (size_t)qg * 1024 + kv0;
        float sv[4];
#pragma unroll
        for (int ni = 0; ni < 4; ++ni) {
          int tm = trow[ni * 16 + lr];
          float val = s[mi][ni][j] * 0.125f;
          sv[ni] = (km[ni] != 0 && tm != 0) ? val : -1e9f;  // exact ref semantics
        }
        float rm = fmaxf(fmaxf(sv[0], sv[1]), fmaxf(sv[2], sv[3]));
#pragma unroll
        for (int dd = 1; dd < 16; dd <<= 1) rm = fmaxf(rm, __shfl_xor(rm, dd, 64));
        float mold = mrun[mi][j];
        float mnew = fmaxf(mold, rm);
        float sf = __expf(mold - mnew);
        mrun[mi][j] = mnew;
        float rs = 0.f;
#pragma unroll
        for (int ni = 0; ni < 4; ++ni) {
          float p = __expf(sv[ni] - mnew);
          s[mi][ni][j] = p;
          rs += p;
        }
#pragma unroll
        for (int dd = 1; dd < 16; dd <<= 1) rs += __shfl_xor(rs, dd, 64);
        lrun[mi][j] = lrun[mi][j] * sf + rs;
#pragma unroll
        for (int nd = 0; nd < 4; ++nd) o[mi][nd][j] *= sf;
      }
    }
    // P -> LDS (bf16)
#pragma unroll
    for (int mi = 0; mi < 2; ++mi)
#pragma unroll
      for (int ni = 0; ni < 4; ++ni)
#pragma unroll
        for (int j = 0; j < 4; ++j)
          Ps[(w * 32 + mi * 16 + lg * 4 + j) * 64 + ni * 16 + lr] = f2bf(s[mi][ni][j]);

    // O += P V  (P rows are wave-private; Vs synced at the top barrier)
#pragma unroll
    for (int ks = 0; ks < 2; ++ks) {
      bf16x8 pa[2], vb[4];
#pragma unroll
      for (int mi = 0; mi < 2; ++mi)
        pa[mi] = *(const bf16x8*)&Ps[(w * 32 + mi * 16 + lr) * 64 + ks * 32 + lg * 8];
#pragma unroll
      for (int nd = 0; nd < 4; ++nd)
        vb[nd] = *(const bf16x8*)&Vs[(nd * 16 + lr) * 64 + ks * 32 + lg * 8];
#pragma unroll
      for (int mi = 0; mi < 2; ++mi)
#pragma unroll
        for (int nd = 0; nd < 4; ++nd)
          o[mi][nd] = __builtin_amdgcn_mfma_f32_16x16x32_bf16(pa[mi], vb[nd], o[mi][nd], 0, 0, 0);
    }
    __syncthreads();  // protect K/V/P before next stage
  }

  // epilogue: x (B,N,C) bf16, c = h*64 + d
  short* xb = x + ((size_t)b * 1024) * 1024 + h * 64;
#pragma unroll
  for (int mi = 0; mi < 2; ++mi)
#pragma unroll
    for (int j = 0; j < 4; ++j) {
      int qg = qt * 128 + w * 32 + mi * 16 + lg * 4 + j;
      float inv = 1.0f / lrun[mi][j];
#pragma unroll
      for (int nd = 0; nd < 4; ++nd) {
        int d = nd * 16 + lr;
        xb[(size_t)qg * 1024 + d] = f2bf(o[mi][nd][j] * inv);
      }
    }
}

// ---------- output GEMM: x(8192x1024 bf16) @ Wot^T + bo -> fp32 ----------
__global__ __launch_bounds__(256, 2) void gemm_out(
    const short* __restrict__ X, const short* __restrict__ Wot,
    const float* __restrict__ bo, float* __restrict__ out) {
  __shared__ __align__(16) short As[128 * 64];
  __shared__ __align__(16) short Bs[128 * 64];
  int tid = threadIdx.x, lane = tid & 63, w = tid >> 6;
  int wm = w >> 1, wn = w & 1, lr = lane & 15, lg = lane >> 4;
  int bm = blockIdx.x * 128, bn = blockIdx.y * 128;

  const f32x4 fz = {0.f, 0.f, 0.f, 0.f};
  f32x4 acc[4][4];
#pragma unroll
  for (int i = 0; i < 4; ++i)
#pragma unroll
    for (int j = 0; j < 4; ++j) acc[i][j] = fz;

  const char* xbase = (const char*)X;
  const char* wbase = (const char*)Wot;

  for (int kt = 0; kt < 1024; kt += 64) {
#pragma unroll
    for (int i = 0; i < 4; ++i) {
      int c = w * 4 + i;
      const char* srcA = xbase + (size_t)(bm + c * 8 + (lane >> 3)) * 2048 + kt * 2 + (lane & 7) * 16;
      gload_lds16(srcA, (char*)As + c * 1024);
      const char* srcB = wbase + (size_t)(bn + c * 8 + (lane >> 3)) * 2048 + kt * 2 + (lane & 7) * 16;
      gload_lds16(srcB, (char*)Bs + c * 1024);
    }
    __syncthreads();
#pragma unroll
    for (int ks = 0; ks < 2; ++ks) {
      bf16x8 af[4], bfr[4];
#pragma unroll
      for (int mi = 0; mi < 4; ++mi)
        af[mi] = *(const bf16x8*)&As[(wm * 64 + mi * 16 + lr) * 64 + ks * 32 + lg * 8];
#pragma unroll
      for (int ni = 0; ni < 4; ++ni)
        bfr[ni] = *(const bf16x8*)&Bs[(wn * 64 + ni * 16 + lr) * 64 + ks * 32 + lg * 8];
#pragma unroll
      for (int mi = 0; mi < 4; ++mi)
#pragma unroll
        for (int ni = 0; ni < 4; ++ni)
          acc[mi][ni] = __builtin_amdgcn_mfma_f32_16x16x32_bf16(af[mi], bfr[ni], acc[mi][ni], 0, 0, 0);
    }
    __syncthreads();
  }
#pragma unroll
  for (int mi = 0; mi < 4; ++mi)
#pragma unroll
    for (int ni = 0; ni < 4; ++ni) {
      int ccol = bn + wn * 64 + ni * 16 + lr;
      float bias = bo[ccol];
#pragma unroll
      for (int j = 0; j < 4; ++j) {
        int r = bm + wm * 64 + mi * 16 + lg * 4 + j;
        out[(size_t)r * 1024 + ccol] = acc[mi][ni][j] + bias;
      }
    }
}

extern "C" void kernel_launch(void* const* d_in, const int* in_sizes, int n_in,
                              void* d_out, int out_size, void* d_ws, size_t ws_size,
                              hipStream_t stream) {
  const float* q = (const float*)d_in[0];
  const float* k = (const float*)d_in[1];
  const float* v = (const float*)d_in[2];
  const int* mask = (const int*)d_in[3];
  const int* tmask = (const int*)d_in[4];
  const float* Wq = (const float*)d_in[5];
  const float* Wk = (const float*)d_in[6];
  const float* Wv = (const float*)d_in[7];
  const float* Wo = (const float*)d_in[8];
  const float* bo = (const float*)d_in[9];
  float* out = (float*)d_out;

  char* ws = (char*)d_ws;
  const size_t MB = 1u << 20;
  if (ws_size < 72 * MB) return;  // fail loudly via wrong output
  short* Wqt = (short*)(ws + 0 * MB);
  short* Wkt = (short*)(ws + 2 * MB);
  short* Wvt = (short*)(ws + 4 * MB);
  short* Wot = (short*)(ws + 6 * MB);
  short* qh  = (short*)(ws + 8 * MB);
  short* kh  = (short*)(ws + 24 * MB);
  short* vh  = (short*)(ws + 40 * MB);
  short* vht = (short*)(ws + 56 * MB);
  short* x   = (short*)(ws + 40 * MB);  // aliases vh (dead after vtrans)

  wconv_t<<<dim3(16, 16), 256, 0, stream>>>(Wq, Wqt);
  wconv_t<<<dim3(16, 16), 256, 0, stream>>>(Wk, Wkt);
  wconv_t<<<dim3(16, 16), 256, 0, stream>>>(Wv, Wvt);
  wconv_t<<<dim3(16, 16), 256, 0, stream>>>(Wo, Wot);

  gemm_qkv<<<dim3(64, 8, 3), 256, 0, stream>>>(q, k, v, Wqt, Wkt, Wvt, qh, kh, vh);
  vtrans<<<dim3(16, 128), 256, 0, stream>>>(vh, vht);
  attn<<<dim3(8, 128), 256, 0, stream>>>(qh, kh, vht, mask, tmask, x);
  gemm_out<<<dim3(64, 8), 256, 0, stream>>>(x, Wot, bo, out);
}

// Round 3
// 415.090 us; speedup vs baseline: 1.1615x; 1.1615x over previous
//
#include <hip/hip_runtime.h>
#include <hip/hip_bf16.h>

#define DEV __device__ __forceinline__

typedef __attribute__((ext_vector_type(8))) short bf16x8;
typedef __attribute__((ext_vector_type(4))) short s16x4;
typedef __attribute__((ext_vector_type(4))) float f32x4;
typedef unsigned int u32;
typedef unsigned long long u64;

DEV short f2bf(float f) {
  union { float f; u32 u; } x; x.f = f;
  u32 r = x.u + 0x7fffu + ((x.u >> 16) & 1u);   // RNE
  return (short)(r >> 16);
}

DEV void gload_lds16(const void* g, void* l) {
  __builtin_amdgcn_global_load_lds(
      (const __attribute__((address_space(1))) u32*)g,
      (__attribute__((address_space(3))) u32*)l, 16, 0, 0);
}

// ---------- combined mask -> packed bits: pk[b][n][16] u64 ----------
__global__ __launch_bounds__(256) void pack_mask(const int* __restrict__ mask,
                                                 const int* __restrict__ tmask,
                                                 u64* __restrict__ pk) {
  int bn = blockIdx.x;                 // (b*1024 + n)
  int b = bn >> 10;
  int t = threadIdx.x, w = t >> 6, lane = t & 63;
  const int* tr = tmask + (size_t)bn * 1024;
  const int* mr = mask + b * 1024;
#pragma unroll
  for (int it = 0; it < 4; ++it) {
    int m = it * 256 + w * 64 + lane;
    bool on = (mr[m] != 0) && (tr[m] != 0);
    u64 bits = __ballot(on);
    if (lane == 0) pk[(size_t)bn * 16 + it * 4 + w] = bits;
  }
}

// ---------- weight fp32 (K x N) -> bf16 transposed (N x K) ----------
__global__ __launch_bounds__(256) void wconv_t(const float* __restrict__ W,
                                               short* __restrict__ Wt) {
  __shared__ short tile[64][65];
  int k0 = blockIdx.x * 64, n0 = blockIdx.y * 64;
  int t = threadIdx.x;
  int r = t >> 2, c = (t & 3) * 16;
  const float* src = W + (size_t)(k0 + r) * 1024 + n0 + c;
#pragma unroll
  for (int i = 0; i < 16; i += 4) {
    float4 f = *(const float4*)(src + i);
    tile[r][c + i + 0] = f2bf(f.x);
    tile[r][c + i + 1] = f2bf(f.y);
    tile[r][c + i + 2] = f2bf(f.z);
    tile[r][c + i + 3] = f2bf(f.w);
  }
  __syncthreads();
  bf16x8 v0, v1;
#pragma unroll
  for (int i = 0; i < 8; ++i) v0[i] = tile[c + i][r];
#pragma unroll
  for (int i = 0; i < 8; ++i) v1[i] = tile[c + 8 + i][r];
  short* dst = Wt + (size_t)(n0 + r) * 1024 + k0 + c;
  *(bf16x8*)(dst) = v0;
  *(bf16x8*)(dst + 8) = v1;
}

// ---------- vh (B,H,M,D) -> vht (B,H,D,M), bf16 ----------
__global__ __launch_bounds__(256) void vtrans(const short* __restrict__ vh,
                                              short* __restrict__ vht) {
  __shared__ short tile[64][65];
  int m0 = blockIdx.x * 64;
  int bh = blockIdx.y;
  int t = threadIdx.x;
  int r = t >> 2, c = (t & 3) * 16;
  const short* src = vh + ((size_t)bh * 1024 + m0 + r) * 64 + c;
  bf16x8 a0 = *(const bf16x8*)(src);
  bf16x8 a1 = *(const bf16x8*)(src + 8);
#pragma unroll
  for (int i = 0; i < 8; ++i) tile[r][c + i] = a0[i];
#pragma unroll
  for (int i = 0; i < 8; ++i) tile[r][c + 8 + i] = a1[i];
  __syncthreads();
  bf16x8 v0, v1;
#pragma unroll
  for (int i = 0; i < 8; ++i) v0[i] = tile[c + i][r];
#pragma unroll
  for (int i = 0; i < 8; ++i) v1[i] = tile[c + 8 + i][r];
  short* dst = vht + ((size_t)bh * 64 + r) * 1024 + m0 + c;
  *(bf16x8*)dst = v0;
  *(bf16x8*)(dst + 8) = v1;
}

// ---------- QKV projection GEMM ----------
// qh is pre-scaled by 0.125*log2(e) so attention can use exp2 directly.
#define QSCALE 0.18033688011112042f

__global__ __launch_bounds__(256, 2) void gemm_qkv(
    const float* __restrict__ Aq, const float* __restrict__ Ak, const float* __restrict__ Av,
    const short* __restrict__ Wqt, const short* __restrict__ Wkt, const short* __restrict__ Wvt,
    short* __restrict__ qh, short* __restrict__ kh, short* __restrict__ vh) {
  // XCD-aware swizzle: 8 n-tiles of one m-panel land contiguously on one XCD.
  int flat = blockIdx.z * 512 + blockIdx.y * 8 + blockIdx.x;
  int nid = (flat & 7) * 192 + (flat >> 3);
  int zz = nid >> 9;
  int rr = nid & 511;
  int bm = (rr >> 3) * 128, bn = (rr & 7) * 128;

  const float* A; const short* Wt; short* Ch; float cs;
  if (zz == 0)      { A = Aq; Wt = Wqt; Ch = qh; cs = QSCALE; }
  else if (zz == 1) { A = Ak; Wt = Wkt; Ch = kh; cs = 1.0f; }
  else              { A = Av; Wt = Wvt; Ch = vh; cs = 1.0f; }

  __shared__ __align__(16) short As[128 * 64];  // [m][k]
  __shared__ __align__(16) short Bs[128 * 64];  // [n][k]

  int tid = threadIdx.x;
  int lane = tid & 63, w = tid >> 6;
  int wm = w >> 1, wn = w & 1;
  int lr = lane & 15, lg = lane >> 4;

  const f32x4 fz = {0.f, 0.f, 0.f, 0.f};
  f32x4 acc[4][4];
#pragma unroll
  for (int i = 0; i < 4; ++i)
#pragma unroll
    for (int j = 0; j < 4; ++j) acc[i][j] = fz;

  int arow = tid >> 1, ahalf = tid & 1;
  const float* abase = A + (size_t)(bm + arow) * 1024 + ahalf * 32;
  short* adst = &As[arow * 64 + ahalf * 32];
  const char* wbase = (const char*)Wt;

  for (int kt = 0; kt < 1024; kt += 64) {
#pragma unroll
    for (int i = 0; i < 8; ++i) {
      float4 f = *(const float4*)(abase + kt + i * 4);
      s16x4 s;
      s[0] = f2bf(f.x); s[1] = f2bf(f.y); s[2] = f2bf(f.z); s[3] = f2bf(f.w);
      *(s16x4*)(adst + i * 4) = s;
    }
#pragma unroll
    for (int i = 0; i < 4; ++i) {
      int c = w * 4 + i;
      const char* src = wbase + (size_t)(bn + c * 8 + (lane >> 3)) * 2048 + kt * 2 + (lane & 7) * 16;
      gload_lds16(src, (char*)Bs + c * 1024);
    }
    __syncthreads();
#pragma unroll
    for (int ks = 0; ks < 2; ++ks) {
      bf16x8 af[4], bfr[4];
#pragma unroll
      for (int mi = 0; mi < 4; ++mi)
        af[mi] = *(const bf16x8*)&As[(wm * 64 + mi * 16 + lr) * 64 + ks * 32 + lg * 8];
#pragma unroll
      for (int ni = 0; ni < 4; ++ni)
        bfr[ni] = *(const bf16x8*)&Bs[(wn * 64 + ni * 16 + lr) * 64 + ks * 32 + lg * 8];
#pragma unroll
      for (int mi = 0; mi < 4; ++mi)
#pragma unroll
        for (int ni = 0; ni < 4; ++ni)
          acc[mi][ni] = __builtin_amdgcn_mfma_f32_16x16x32_bf16(af[mi], bfr[ni], acc[mi][ni], 0, 0, 0);
    }
    __syncthreads();
  }
#pragma unroll
  for (int mi = 0; mi < 4; ++mi)
#pragma unroll
    for (int ni = 0; ni < 4; ++ni) {
      int ccol = bn + wn * 64 + ni * 16 + lr;
      int h = ccol >> 6, d = ccol & 63;
#pragma unroll
      for (int j = 0; j < 4; ++j) {
        int r = bm + wm * 64 + mi * 16 + lg * 4 + j;
        int bb = r >> 10, n = r & 1023;
        Ch[(((size_t)bb * 16 + h) * 1024 + n) * 64 + d] = f2bf(acc[mi][ni][j] * cs);
      }
    }
}

// ---------- flash attention (no-max softmax, packed masks, swizzled LDS, dbuf) ----------
DEV void stage_kv(const char* kbase, const char* vbase, int kv0,
                  short* Ksb, short* Vsb, int w, int lane) {
#pragma unroll
  for (int i = 0; i < 2; ++i) {
    int c = w * 2 + i;
    int row = (lane >> 3);                       // row&7 within 8-row chunk
    int colb = ((lane & 7) ^ row) << 4;          // pre-swizzled source column
    gload_lds16(kbase + (size_t)(kv0 + c * 8 + row) * 128 + colb, (char*)Ksb + c * 1024);
    gload_lds16(vbase + (size_t)(c * 8 + row) * 2048 + kv0 * 2 + colb, (char*)Vsb + c * 1024);
  }
}

__global__ __launch_bounds__(256, 2) void attn(
    const short* __restrict__ qh, const short* __restrict__ kh, const short* __restrict__ vht,
    const u64* __restrict__ pk, short* __restrict__ x) {
  __shared__ __align__(16) short Ks[2][4096];   // [key][d], XOR-swizzled
  __shared__ __align__(16) short Vs[2][4096];   // [d][key], XOR-swizzled
  __shared__ __align__(16) short Ps[8192];      // [qrow][key], XOR-swizzled

  int flat = blockIdx.y * 8 + blockIdx.x;       // grid (8 qt, 128 bh)
  int nid = (flat & 7) * 128 + (flat >> 3);     // XCD chunking: q-tiles of a head co-locate
  int bh = nid >> 3, qt = nid & 7;
  int b = bh >> 4;
  int tid = threadIdx.x, lane = tid & 63, w = tid >> 6;
  int lr = lane & 15, lg = lane >> 4;

  bf16x8 qa[2][2];
  {
    const short* qb = qh + ((size_t)bh * 1024 + qt * 128 + w * 32) * 64;
#pragma unroll
    for (int mi = 0; mi < 2; ++mi)
#pragma unroll
      for (int ks = 0; ks < 2; ++ks)
        qa[mi][ks] = *(const bf16x8*)(qb + (mi * 16 + lr) * 64 + ks * 32 + lg * 8);
  }

  const f32x4 fz = {0.f, 0.f, 0.f, 0.f};
  f32x4 o[2][4];
  float psum[2][4];
#pragma unroll
  for (int mi = 0; mi < 2; ++mi)
#pragma unroll
    for (int j = 0; j < 4; ++j) psum[mi][j] = 0.f;
#pragma unroll
  for (int mi = 0; mi < 2; ++mi)
#pragma unroll
    for (int nd = 0; nd < 4; ++nd) o[mi][nd] = fz;

  const char* kbase = (const char*)(kh + (size_t)bh * 65536);
  const char* vbase = (const char*)(vht + (size_t)bh * 65536);
  const u64* pkb = pk + ((size_t)b * 1024 + qt * 128) * 16;

  stage_kv(kbase, vbase, 0, Ks[0], Vs[0], w, lane);
  __syncthreads();
  int cur = 0;

  for (int t = 0; t < 16; ++t) {
    if (t < 15) stage_kv(kbase, vbase, (t + 1) * 64, Ks[cur ^ 1], Vs[cur ^ 1], w, lane);

    // packed mask words (L2-resident broadcast loads) — issue early
    u64 pw[2][4];
#pragma unroll
    for (int mi = 0; mi < 2; ++mi)
#pragma unroll
      for (int j = 0; j < 4; ++j)
        pw[mi][j] = pkb[(w * 32 + mi * 16 + lg * 4 + j) * 16 + t];

    // S = Q K^T  (qh pre-scaled by 0.125*log2e)
    f32x4 s[2][4];
#pragma unroll
    for (int mi = 0; mi < 2; ++mi)
#pragma unroll
      for (int ni = 0; ni < 4; ++ni) s[mi][ni] = fz;
#pragma unroll
    for (int ks = 0; ks < 2; ++ks) {
      bf16x8 kb[4];
#pragma unroll
      for (int ni = 0; ni < 4; ++ni)
        kb[ni] = *(const bf16x8*)&Ks[cur][(ni * 16 + lr) * 64 + ((ks * 32 + lg * 8) ^ ((lr & 7) << 3))];
#pragma unroll
      for (int mi = 0; mi < 2; ++mi)
#pragma unroll
        for (int ni = 0; ni < 4; ++ni)
          s[mi][ni] = __builtin_amdgcn_mfma_f32_16x16x32_bf16(qa[mi][ks], kb[ni], s[mi][ni], 0, 0, 0);
    }

    // P = mask ? exp2(S) : 0 ; accumulate row sums per-lane (no max tracking)
#pragma unroll
    for (int mi = 0; mi < 2; ++mi)
#pragma unroll
      for (int j = 0; j < 4; ++j) {
        u32 lo = (u32)pw[mi][j], hi = (u32)(pw[mi][j] >> 32);
        float rs = 0.f;
#pragma unroll
        for (int ni = 0; ni < 4; ++ni) {
          u32 bit = ((ni < 2 ? lo : hi) >> ((ni & 1) * 16 + lr)) & 1u;
          float e = __builtin_amdgcn_exp2f(s[mi][ni][j]);
          float p = bit ? e : 0.f;
          s[mi][ni][j] = p;
          rs += p;
        }
        psum[mi][j] += rs;
      }

    // P -> LDS (bf16, swizzled)
#pragma unroll
    for (int mi = 0; mi < 2; ++mi)
#pragma unroll
      for (int j = 0; j < 4; ++j) {
        int r = w * 32 + mi * 16 + lg * 4 + j;
        int sw = (r & 7) << 3;
#pragma unroll
        for (int ni = 0; ni < 4; ++ni)
          Ps[r * 64 + ((ni * 16 + lr) ^ sw)] = f2bf(s[mi][ni][j]);
      }

    // O += P V
#pragma unroll
    for (int ks = 0; ks < 2; ++ks) {
      bf16x8 pa[2], vb[4];
#pragma unroll
      for (int mi = 0; mi < 2; ++mi)
        pa[mi] = *(const bf16x8*)&Ps[(w * 32 + mi * 16 + lr) * 64 + ((ks * 32 + lg * 8) ^ ((lr & 7) << 3))];
#pragma unroll
      for (int nd = 0; nd < 4; ++nd)
        vb[nd] = *(const bf16x8*)&Vs[cur][(nd * 16 + lr) * 64 + ((ks * 32 + lg * 8) ^ ((lr & 7) << 3))];
#pragma unroll
      for (int mi = 0; mi < 2; ++mi)
#pragma unroll
        for (int nd = 0; nd < 4; ++nd)
          o[mi][nd] = __builtin_amdgcn_mfma_f32_16x16x32_bf16(pa[mi], vb[nd], o[mi][nd], 0, 0, 0);
    }
    __syncthreads();
    cur ^= 1;
  }

  // epilogue: one sum-reduction tree per row, then normalize + store
  short* xb = x + ((size_t)b * 1024) * 1024 + (bh & 15) * 64;
#pragma unroll
  for (int mi = 0; mi < 2; ++mi)
#pragma unroll
    for (int j = 0; j < 4; ++j) {
      float rs = psum[mi][j];
#pragma unroll
      for (int dd = 1; dd < 16; dd <<= 1) rs += __shfl_xor(rs, dd, 64);
      float inv = rs > 0.f ? 1.0f / rs : 0.f;
      int qg = qt * 128 + w * 32 + mi * 16 + lg * 4 + j;
#pragma unroll
      for (int nd = 0; nd < 4; ++nd) {
        int d = nd * 16 + lr;
        xb[(size_t)qg * 1024 + d] = f2bf(o[mi][nd][j] * inv);
      }
    }
}

// ---------- output GEMM: x(8192x1024 bf16) @ Wot^T + bo -> fp32 ----------
__global__ __launch_bounds__(256, 2) void gemm_out(
    const short* __restrict__ X, const short* __restrict__ Wot,
    const float* __restrict__ bo, float* __restrict__ out) {
  int flat = blockIdx.y * 8 + blockIdx.x;       // grid (8 n, 64 m)
  int nid = (flat & 7) * 64 + (flat >> 3);
  int bm = (nid >> 3) * 128, bn = (nid & 7) * 128;

  __shared__ __align__(16) short As[128 * 64];
  __shared__ __align__(16) short Bs[128 * 64];
  int tid = threadIdx.x, lane = tid & 63, w = tid >> 6;
  int wm = w >> 1, wn = w & 1, lr = lane & 15, lg = lane >> 4;

  const f32x4 fz = {0.f, 0.f, 0.f, 0.f};
  f32x4 acc[4][4];
#pragma unroll
  for (int i = 0; i < 4; ++i)
#pragma unroll
    for (int j = 0; j < 4; ++j) acc[i][j] = fz;

  const char* xbase = (const char*)X;
  const char* wbase = (const char*)Wot;

  for (int kt = 0; kt < 1024; kt += 64) {
#pragma unroll
    for (int i = 0; i < 4; ++i) {
      int c = w * 4 + i;
      const char* srcA = xbase + (size_t)(bm + c * 8 + (lane >> 3)) * 2048 + kt * 2 + (lane & 7) * 16;
      gload_lds16(srcA, (char*)As + c * 1024);
      const char* srcB = wbase + (size_t)(bn + c * 8 + (lane >> 3)) * 2048 + kt * 2 + (lane & 7) * 16;
      gload_lds16(srcB, (char*)Bs + c * 1024);
    }
    __syncthreads();
#pragma unroll
    for (int ks = 0; ks < 2; ++ks) {
      bf16x8 af[4], bfr[4];
#pragma unroll
      for (int mi = 0; mi < 4; ++mi)
        af[mi] = *(const bf16x8*)&As[(wm * 64 + mi * 16 + lr) * 64 + ks * 32 + lg * 8];
#pragma unroll
      for (int ni = 0; ni < 4; ++ni)
        bfr[ni] = *(const bf16x8*)&Bs[(wn * 64 + ni * 16 + lr) * 64 + ks * 32 + lg * 8];
#pragma unroll
      for (int mi = 0; mi < 4; ++mi)
#pragma unroll
        for (int ni = 0; ni < 4; ++ni)
          acc[mi][ni] = __builtin_amdgcn_mfma_f32_16x16x32_bf16(af[mi], bfr[ni], acc[mi][ni], 0, 0, 0);
    }
    __syncthreads();
  }
#pragma unroll
  for (int mi = 0; mi < 4; ++mi)
#pragma unroll
    for (int ni = 0; ni < 4; ++ni) {
      int ccol = bn + wn * 64 + ni * 16 + lr;
      float bias = bo[ccol];
#pragma unroll
      for (int j = 0; j < 4; ++j) {
        int r = bm + wm * 64 + mi * 16 + lg * 4 + j;
        out[(size_t)r * 1024 + ccol] = acc[mi][ni][j] + bias;
      }
    }
}

extern "C" void kernel_launch(void* const* d_in, const int* in_sizes, int n_in,
                              void* d_out, int out_size, void* d_ws, size_t ws_size,
                              hipStream_t stream) {
  const float* q = (const float*)d_in[0];
  const float* k = (const float*)d_in[1];
  const float* v = (const float*)d_in[2];
  const int* mask = (const int*)d_in[3];
  const int* tmask = (const int*)d_in[4];
  const float* Wq = (const float*)d_in[5];
  const float* Wk = (const float*)d_in[6];
  const float* Wv = (const float*)d_in[7];
  const float* Wo = (const float*)d_in[8];
  const float* bo = (const float*)d_in[9];
  float* out = (float*)d_out;

  char* ws = (char*)d_ws;
  const size_t MB = 1u << 20;
  if (ws_size < 72 * MB) return;
  short* Wqt = (short*)(ws + 0 * MB);
  short* Wkt = (short*)(ws + 2 * MB);
  short* Wvt = (short*)(ws + 4 * MB);
  short* Wot = (short*)(ws + 6 * MB);
  short* qh  = (short*)(ws + 8 * MB);
  short* kh  = (short*)(ws + 24 * MB);
  short* vh  = (short*)(ws + 40 * MB);
  short* vht = (short*)(ws + 56 * MB);
  short* x   = (short*)(ws + 40 * MB);  // aliases vh (dead after vtrans)
  u64*   pkb = (u64*)d_out;             // 1 MB of d_out used as scratch; fully
                                        // overwritten by gemm_out at the end.

  pack_mask<<<dim3(8192), 256, 0, stream>>>(mask, tmask, pkb);
  wconv_t<<<dim3(16, 16), 256, 0, stream>>>(Wq, Wqt);
  wconv_t<<<dim3(16, 16), 256, 0, stream>>>(Wk, Wkt);
  wconv_t<<<dim3(16, 16), 256, 0, stream>>>(Wv, Wvt);
  wconv_t<<<dim3(16, 16), 256, 0, stream>>>(Wo, Wot);

  gemm_qkv<<<dim3(8, 64, 3), 256, 0, stream>>>(q, k, v, Wqt, Wkt, Wvt, qh, kh, vh);
  vtrans<<<dim3(16, 128), 256, 0, stream>>>(vh, vht);
  attn<<<dim3(8, 128), 256, 0, stream>>>(qh, kh, vht, pkb, x);
  gemm_out<<<dim3(8, 64), 256, 0, stream>>>(x, Wot, bo, out);
}

// Round 4
// 350.654 us; speedup vs baseline: 1.3749x; 1.1838x over previous
//
#include <hip/hip_runtime.h>
#include <hip/hip_bf16.h>

#define DEV __device__ __forceinline__

typedef __attribute__((ext_vector_type(8))) short bf16x8;
typedef __attribute__((ext_vector_type(4))) float f32x4;
typedef unsigned int u32;
typedef unsigned long long u64;

DEV short f2bf(float f) {
  union { float f; u32 u; } x; x.f = f;
  u32 r = x.u + 0x7fffu + ((x.u >> 16) & 1u);   // RNE
  return (short)(r >> 16);
}

DEV void gload_lds16(const void* g, void* l) {
  __builtin_amdgcn_global_load_lds(
      (const __attribute__((address_space(1))) u32*)g,
      (__attribute__((address_space(3))) u32*)l, 16, 0, 0);
}

// Stage a 128-row x 64-short bf16 tile (row stride 2048 B in global) into LDS,
// linear dest, XOR-pre-swizzled source (rule #21: swizzle source + read, dest linear).
DEV void stage_t128(const char* base, int ktb, char* lds, int w, int lane) {
  int r8 = lane >> 3;                       // row within 8-row stripe
  int csw = ((lane & 7) ^ r8) << 4;         // swizzled 16B-chunk column
#pragma unroll
  for (int i = 0; i < 4; ++i) {
    int c = w * 4 + i;
    gload_lds16(base + (size_t)(c * 8 + r8) * 2048 + ktb + csw, lds + c * 1024);
  }
}

// XOR-swizzled fragment read matching stage_t128 layout. col in shorts.
DEV bf16x8 frag(const short* L, int row, int col) {
  return *(const bf16x8*)&L[row * 64 + (col ^ ((row & 7) << 3))];
}

// ---------- activations fp32 -> bf16 (once) ----------
__global__ __launch_bounds__(256) void aconv(const float* __restrict__ q,
    const float* __restrict__ k, const float* __restrict__ v,
    short* __restrict__ qb, short* __restrict__ kb, short* __restrict__ vb) {
  const float* src; short* dst;
  if (blockIdx.z == 0)      { src = q; dst = qb; }
  else if (blockIdx.z == 1) { src = k; dst = kb; }
  else                      { src = v; dst = vb; }
  size_t i = ((size_t)blockIdx.x * 256 + threadIdx.x) * 8;
  float4 f0 = *(const float4*)(src + i);
  float4 f1 = *(const float4*)(src + i + 4);
  bf16x8 o;
  o[0] = f2bf(f0.x); o[1] = f2bf(f0.y); o[2] = f2bf(f0.z); o[3] = f2bf(f0.w);
  o[4] = f2bf(f1.x); o[5] = f2bf(f1.y); o[6] = f2bf(f1.z); o[7] = f2bf(f1.w);
  *(bf16x8*)(dst + i) = o;
}

// ---------- combined mask -> packed bits: pk[b][n][16] u64 ----------
__global__ __launch_bounds__(256) void pack_mask(const int* __restrict__ mask,
                                                 const int* __restrict__ tmask,
                                                 u64* __restrict__ pk) {
  int bn = blockIdx.x;                 // (b*1024 + n)
  int b = bn >> 10;
  int t = threadIdx.x, w = t >> 6, lane = t & 63;
  const int* tr = tmask + (size_t)bn * 1024;
  const int* mr = mask + b * 1024;
#pragma unroll
  for (int it = 0; it < 4; ++it) {
    int m = it * 256 + w * 64 + lane;
    bool on = (mr[m] != 0) && (tr[m] != 0);
    u64 bits = __ballot(on);
    if (lane == 0) pk[(size_t)bn * 16 + it * 4 + w] = bits;
  }
}

// ---------- 4 weights fp32 (K x N) -> bf16 transposed (N x K), fused ----------
__global__ __launch_bounds__(256) void wconv4(const float* __restrict__ W0,
    const float* __restrict__ W1, const float* __restrict__ W2,
    const float* __restrict__ W3, short* __restrict__ WtAll) {
  const float* W = blockIdx.z == 0 ? W0 : blockIdx.z == 1 ? W1
                 : blockIdx.z == 2 ? W2 : W3;
  short* Wt = WtAll + (size_t)blockIdx.z * 1024 * 1024;
  __shared__ short tile[64][65];
  int k0 = blockIdx.x * 64, n0 = blockIdx.y * 64;
  int t = threadIdx.x;
  int r = t >> 2, c = (t & 3) * 16;
  const float* src = W + (size_t)(k0 + r) * 1024 + n0 + c;
#pragma unroll
  for (int i = 0; i < 16; i += 4) {
    float4 f = *(const float4*)(src + i);
    tile[r][c + i + 0] = f2bf(f.x);
    tile[r][c + i + 1] = f2bf(f.y);
    tile[r][c + i + 2] = f2bf(f.z);
    tile[r][c + i + 3] = f2bf(f.w);
  }
  __syncthreads();
  bf16x8 v0, v1;
#pragma unroll
  for (int i = 0; i < 8; ++i) v0[i] = tile[c + i][r];
#pragma unroll
  for (int i = 0; i < 8; ++i) v1[i] = tile[c + 8 + i][r];
  short* dst = Wt + (size_t)(n0 + r) * 1024 + k0 + c;
  *(bf16x8*)(dst) = v0;
  *(bf16x8*)(dst + 8) = v1;
}

// ---------- vh (B,H,M,D) -> vht (B,H,D,M), bf16 ----------
__global__ __launch_bounds__(256) void vtrans(const short* __restrict__ vh,
                                              short* __restrict__ vht) {
  __shared__ short tile[64][65];
  int m0 = blockIdx.x * 64;
  int bh = blockIdx.y;
  int t = threadIdx.x;
  int r = t >> 2, c = (t & 3) * 16;
  const short* src = vh + ((size_t)bh * 1024 + m0 + r) * 64 + c;
  bf16x8 a0 = *(const bf16x8*)(src);
  bf16x8 a1 = *(const bf16x8*)(src + 8);
#pragma unroll
  for (int i = 0; i < 8; ++i) tile[r][c + i] = a0[i];
#pragma unroll
  for (int i = 0; i < 8; ++i) tile[r][c + 8 + i] = a1[i];
  __syncthreads();
  bf16x8 v0, v1;
#pragma unroll
  for (int i = 0; i < 8; ++i) v0[i] = tile[c + i][r];
#pragma unroll
  for (int i = 0; i < 8; ++i) v1[i] = tile[c + 8 + i][r];
  short* dst = vht + ((size_t)bh * 64 + r) * 1024 + m0 + c;
  *(bf16x8*)dst = v0;
  *(bf16x8*)(dst + 8) = v1;
}

// ---------- QKV projection GEMM (all-bf16 operands via gload_lds, swizzled) ----------
// qh is pre-scaled by 0.125*log2(e) so attention can use exp2 directly.
#define QSCALE 0.18033688011112042f

__global__ __launch_bounds__(256, 2) void gemm_qkv(
    const short* __restrict__ qb, const short* __restrict__ kb, const short* __restrict__ vb,
    const short* __restrict__ WtAll,
    short* __restrict__ qh, short* __restrict__ kh, short* __restrict__ vh) {
  // XCD-aware swizzle: 8 n-tiles of one m-panel land contiguously on one XCD.
  int flat = blockIdx.z * 512 + blockIdx.y * 8 + blockIdx.x;
  int nid = (flat & 7) * 192 + (flat >> 3);
  int zz = nid >> 9;
  int rr = nid & 511;
  int bm = (rr >> 3) * 128, bn = (rr & 7) * 128;

  const short* A; short* Ch; float cs;
  if (zz == 0)      { A = qb; Ch = qh; cs = QSCALE; }
  else if (zz == 1) { A = kb; Ch = kh; cs = 1.0f; }
  else              { A = vb; Ch = vh; cs = 1.0f; }
  const short* Wt = WtAll + (size_t)zz * 1024 * 1024;

  __shared__ __align__(16) short As[128 * 64];  // [m][k], XOR-swizzled
  __shared__ __align__(16) short Bs[128 * 64];  // [n][k], XOR-swizzled

  int tid = threadIdx.x;
  int lane = tid & 63, w = tid >> 6;
  int wm = w >> 1, wn = w & 1;
  int lr = lane & 15, lg = lane >> 4;

  const f32x4 fz = {0.f, 0.f, 0.f, 0.f};
  f32x4 acc[4][4];
#pragma unroll
  for (int i = 0; i < 4; ++i)
#pragma unroll
    for (int j = 0; j < 4; ++j) acc[i][j] = fz;

  const char* abase = (const char*)A + (size_t)bm * 2048;
  const char* bbase = (const char*)Wt + (size_t)bn * 2048;

  for (int ktb = 0; ktb < 2048; ktb += 128) {
    stage_t128(abase, ktb, (char*)As, w, lane);
    stage_t128(bbase, ktb, (char*)Bs, w, lane);
    __syncthreads();
#pragma unroll
    for (int ks = 0; ks < 2; ++ks) {
      bf16x8 af[4], bfr[4];
#pragma unroll
      for (int mi = 0; mi < 4; ++mi)
        af[mi] = frag(As, wm * 64 + mi * 16 + lr, ks * 32 + lg * 8);
#pragma unroll
      for (int ni = 0; ni < 4; ++ni)
        bfr[ni] = frag(Bs, wn * 64 + ni * 16 + lr, ks * 32 + lg * 8);
#pragma unroll
      for (int mi = 0; mi < 4; ++mi)
#pragma unroll
        for (int ni = 0; ni < 4; ++ni)
          acc[mi][ni] = __builtin_amdgcn_mfma_f32_16x16x32_bf16(af[mi], bfr[ni], acc[mi][ni], 0, 0, 0);
    }
    __syncthreads();
  }
#pragma unroll
  for (int mi = 0; mi < 4; ++mi)
#pragma unroll
    for (int ni = 0; ni < 4; ++ni) {
      int ccol = bn + wn * 64 + ni * 16 + lr;
      int h = ccol >> 6, d = ccol & 63;
#pragma unroll
      for (int j = 0; j < 4; ++j) {
        int r = bm + wm * 64 + mi * 16 + lg * 4 + j;
        int bb = r >> 10, n = r & 1023;
        Ch[(((size_t)bb * 16 + h) * 1024 + n) * 64 + d] = f2bf(acc[mi][ni][j] * cs);
      }
    }
}

// ---------- flash attention (no-max softmax, packed masks, swizzled LDS, dbuf) ----------
DEV void stage_kv(const char* kbase, const char* vbase, int kv0,
                  short* Ksb, short* Vsb, int w, int lane) {
#pragma unroll
  for (int i = 0; i < 2; ++i) {
    int c = w * 2 + i;
    int row = (lane >> 3);
    int colb = ((lane & 7) ^ row) << 4;          // pre-swizzled source column
    gload_lds16(kbase + (size_t)(kv0 + c * 8 + row) * 128 + colb, (char*)Ksb + c * 1024);
    gload_lds16(vbase + (size_t)(c * 8 + row) * 2048 + kv0 * 2 + colb, (char*)Vsb + c * 1024);
  }
}

__global__ __launch_bounds__(256, 2) void attn(
    const short* __restrict__ qh, const short* __restrict__ kh, const short* __restrict__ vht,
    const u64* __restrict__ pk, short* __restrict__ x) {
  __shared__ __align__(16) short Ks[2][4096];   // [key][d], XOR-swizzled
  __shared__ __align__(16) short Vs[2][4096];   // [d][key], XOR-swizzled
  __shared__ __align__(16) short Ps[8192];      // [qrow][key], XOR-swizzled

  int flat = blockIdx.y * 8 + blockIdx.x;       // grid (8 qt, 128 bh)
  int nid = (flat & 7) * 128 + (flat >> 3);     // XCD chunking: q-tiles of a head co-locate
  int bh = nid >> 3, qt = nid & 7;
  int b = bh >> 4;
  int tid = threadIdx.x, lane = tid & 63, w = tid >> 6;
  int lr = lane & 15, lg = lane >> 4;

  bf16x8 qa[2][2];
  {
    const short* qb2 = qh + ((size_t)bh * 1024 + qt * 128 + w * 32) * 64;
#pragma unroll
    for (int mi = 0; mi < 2; ++mi)
#pragma unroll
      for (int ks = 0; ks < 2; ++ks)
        qa[mi][ks] = *(const bf16x8*)(qb2 + (mi * 16 + lr) * 64 + ks * 32 + lg * 8);
  }

  const f32x4 fz = {0.f, 0.f, 0.f, 0.f};
  f32x4 o[2][4];
  float psum[2][4];
#pragma unroll
  for (int mi = 0; mi < 2; ++mi)
#pragma unroll
    for (int j = 0; j < 4; ++j) psum[mi][j] = 0.f;
#pragma unroll
  for (int mi = 0; mi < 2; ++mi)
#pragma unroll
    for (int nd = 0; nd < 4; ++nd) o[mi][nd] = fz;

  const char* kbase = (const char*)(kh + (size_t)bh * 65536);
  const char* vbase = (const char*)(vht + (size_t)bh * 65536);
  const u64* pkb = pk + ((size_t)b * 1024 + qt * 128) * 16;

  stage_kv(kbase, vbase, 0, Ks[0], Vs[0], w, lane);
  __syncthreads();
  int cur = 0;

  for (int t = 0; t < 16; ++t) {
    if (t < 15) stage_kv(kbase, vbase, (t + 1) * 64, Ks[cur ^ 1], Vs[cur ^ 1], w, lane);

    u64 pw[2][4];
#pragma unroll
    for (int mi = 0; mi < 2; ++mi)
#pragma unroll
      for (int j = 0; j < 4; ++j)
        pw[mi][j] = pkb[(w * 32 + mi * 16 + lg * 4 + j) * 16 + t];

    // S = Q K^T  (qh pre-scaled by 0.125*log2e)
    f32x4 s[2][4];
#pragma unroll
    for (int mi = 0; mi < 2; ++mi)
#pragma unroll
      for (int ni = 0; ni < 4; ++ni) s[mi][ni] = fz;
#pragma unroll
    for (int ks = 0; ks < 2; ++ks) {
      bf16x8 kb2[4];
#pragma unroll
      for (int ni = 0; ni < 4; ++ni)
        kb2[ni] = *(const bf16x8*)&Ks[cur][(ni * 16 + lr) * 64 + ((ks * 32 + lg * 8) ^ ((lr & 7) << 3))];
#pragma unroll
      for (int mi = 0; mi < 2; ++mi)
#pragma unroll
        for (int ni = 0; ni < 4; ++ni)
          s[mi][ni] = __builtin_amdgcn_mfma_f32_16x16x32_bf16(qa[mi][ks], kb2[ni], s[mi][ni], 0, 0, 0);
    }

    // P = mask ? exp2(S) : 0 ; accumulate row sums per-lane (no max tracking)
#pragma unroll
    for (int mi = 0; mi < 2; ++mi)
#pragma unroll
      for (int j = 0; j < 4; ++j) {
        u32 lo = (u32)pw[mi][j], hi = (u32)(pw[mi][j] >> 32);
        float rs = 0.f;
#pragma unroll
        for (int ni = 0; ni < 4; ++ni) {
          u32 bit = ((ni < 2 ? lo : hi) >> ((ni & 1) * 16 + lr)) & 1u;
          float e = __builtin_amdgcn_exp2f(s[mi][ni][j]);
          float p = bit ? e : 0.f;
          s[mi][ni][j] = p;
          rs += p;
        }
        psum[mi][j] += rs;
      }

    // P -> LDS (bf16, swizzled)
#pragma unroll
    for (int mi = 0; mi < 2; ++mi)
#pragma unroll
      for (int j = 0; j < 4; ++j) {
        int r = w * 32 + mi * 16 + lg * 4 + j;
        int sw = (r & 7) << 3;
#pragma unroll
        for (int ni = 0; ni < 4; ++ni)
          Ps[r * 64 + ((ni * 16 + lr) ^ sw)] = f2bf(s[mi][ni][j]);
      }

    // O += P V
#pragma unroll
    for (int ks = 0; ks < 2; ++ks) {
      bf16x8 pa[2], vb2[4];
#pragma unroll
      for (int mi = 0; mi < 2; ++mi)
        pa[mi] = *(const bf16x8*)&Ps[(w * 32 + mi * 16 + lr) * 64 + ((ks * 32 + lg * 8) ^ ((lr & 7) << 3))];
#pragma unroll
      for (int nd = 0; nd < 4; ++nd)
        vb2[nd] = *(const bf16x8*)&Vs[cur][(nd * 16 + lr) * 64 + ((ks * 32 + lg * 8) ^ ((lr & 7) << 3))];
#pragma unroll
      for (int mi = 0; mi < 2; ++mi)
#pragma unroll
        for (int nd = 0; nd < 4; ++nd)
          o[mi][nd] = __builtin_amdgcn_mfma_f32_16x16x32_bf16(pa[mi], vb2[nd], o[mi][nd], 0, 0, 0);
    }
    __syncthreads();
    cur ^= 1;
  }

  // epilogue: one sum-reduction tree per row, then normalize + store
  short* xb = x + ((size_t)b * 1024) * 1024 + (bh & 15) * 64;
#pragma unroll
  for (int mi = 0; mi < 2; ++mi)
#pragma unroll
    for (int j = 0; j < 4; ++j) {
      float rs = psum[mi][j];
#pragma unroll
      for (int dd = 1; dd < 16; dd <<= 1) rs += __shfl_xor(rs, dd, 64);
      float inv = rs > 0.f ? 1.0f / rs : 0.f;
      int qg = qt * 128 + w * 32 + mi * 16 + lg * 4 + j;
#pragma unroll
      for (int nd = 0; nd < 4; ++nd) {
        int d = nd * 16 + lr;
        xb[(size_t)qg * 1024 + d] = f2bf(o[mi][nd][j] * inv);
      }
    }
}

// ---------- output GEMM: x(8192x1024 bf16) @ Wot^T + bo -> fp32 ----------
__global__ __launch_bounds__(256, 2) void gemm_out(
    const short* __restrict__ X, const short* __restrict__ Wot,
    const float* __restrict__ bo, float* __restrict__ out) {
  int flat = blockIdx.y * 8 + blockIdx.x;       // grid (8 n, 64 m)
  int nid = (flat & 7) * 64 + (flat >> 3);
  int bm = (nid >> 3) * 128, bn = (nid & 7) * 128;

  __shared__ __align__(16) short As[128 * 64];
  __shared__ __align__(16) short Bs[128 * 64];
  int tid = threadIdx.x, lane = tid & 63, w = tid >> 6;
  int wm = w >> 1, wn = w & 1, lr = lane & 15, lg = lane >> 4;

  const f32x4 fz = {0.f, 0.f, 0.f, 0.f};
  f32x4 acc[4][4];
#pragma unroll
  for (int i = 0; i < 4; ++i)
#pragma unroll
    for (int j = 0; j < 4; ++j) acc[i][j] = fz;

  const char* abase = (const char*)X + (size_t)bm * 2048;
  const char* bbase = (const char*)Wot + (size_t)bn * 2048;

  for (int ktb = 0; ktb < 2048; ktb += 128) {
    stage_t128(abase, ktb, (char*)As, w, lane);
    stage_t128(bbase, ktb, (char*)Bs, w, lane);
    __syncthreads();
#pragma unroll
    for (int ks = 0; ks < 2; ++ks) {
      bf16x8 af[4], bfr[4];
#pragma unroll
      for (int mi = 0; mi < 4; ++mi)
        af[mi] = frag(As, wm * 64 + mi * 16 + lr, ks * 32 + lg * 8);
#pragma unroll
      for (int ni = 0; ni < 4; ++ni)
        bfr[ni] = frag(Bs, wn * 64 + ni * 16 + lr, ks * 32 + lg * 8);
#pragma unroll
      for (int mi = 0; mi < 4; ++mi)
#pragma unroll
        for (int ni = 0; ni < 4; ++ni)
          acc[mi][ni] = __builtin_amdgcn_mfma_f32_16x16x32_bf16(af[mi], bfr[ni], acc[mi][ni], 0, 0, 0);
    }
    __syncthreads();
  }
#pragma unroll
  for (int mi = 0; mi < 4; ++mi)
#pragma unroll
    for (int ni = 0; ni < 4; ++ni) {
      int ccol = bn + wn * 64 + ni * 16 + lr;
      float bias = bo[ccol];
#pragma unroll
      for (int j = 0; j < 4; ++j) {
        int r = bm + wm * 64 + mi * 16 + lg * 4 + j;
        out[(size_t)r * 1024 + ccol] = acc[mi][ni][j] + bias;
      }
    }
}

extern "C" void kernel_launch(void* const* d_in, const int* in_sizes, int n_in,
                              void* d_out, int out_size, void* d_ws, size_t ws_size,
                              hipStream_t stream) {
  const float* q = (const float*)d_in[0];
  const float* k = (const float*)d_in[1];
  const float* v = (const float*)d_in[2];
  const int* mask = (const int*)d_in[3];
  const int* tmask = (const int*)d_in[4];
  const float* Wq = (const float*)d_in[5];
  const float* Wk = (const float*)d_in[6];
  const float* Wv = (const float*)d_in[7];
  const float* Wo = (const float*)d_in[8];
  const float* bo = (const float*)d_in[9];
  float* out = (float*)d_out;

  char* ws = (char*)d_ws;
  const size_t MB = 1u << 20;
  if (ws_size < 73 * MB) return;
  short* WtAll = (short*)(ws + 0 * MB);   // Wqt,Wkt,Wvt,Wot contiguous (8 MB)
  short* qh  = (short*)(ws + 8 * MB);
  short* kh  = (short*)(ws + 24 * MB);
  short* vh  = (short*)(ws + 40 * MB);
  short* vht = (short*)(ws + 56 * MB);
  u64*   pkb = (u64*)(ws + 72 * MB);      // 1 MB packed masks
  short* x   = (short*)(ws + 40 * MB);    // aliases vh (dead after vtrans)
  // qb/kb live in d_out (32 MB, overwritten by gemm_out at the very end);
  // vb aliases the vht region (vht written only later, by vtrans).
  short* qbA = (short*)d_out;
  short* kbA = (short*)d_out + 8 * 1024 * 1024;
  short* vbA = (short*)(ws + 56 * MB);

  aconv<<<dim3(4096, 1, 3), 256, 0, stream>>>(q, k, v, qbA, kbA, vbA);
  wconv4<<<dim3(16, 16, 4), 256, 0, stream>>>(Wq, Wk, Wv, Wo, WtAll);
  pack_mask<<<dim3(8192), 256, 0, stream>>>(mask, tmask, pkb);

  gemm_qkv<<<dim3(8, 64, 3), 256, 0, stream>>>(qbA, kbA, vbA, WtAll, qh, kh, vh);
  vtrans<<<dim3(16, 128), 256, 0, stream>>>(vh, vht);
  attn<<<dim3(8, 128), 256, 0, stream>>>(qh, kh, vht, pkb, x);
  gemm_out<<<dim3(8, 64), 256, 0, stream>>>(x, WtAll + 3 * 1024 * 1024, bo, out);
}

// Round 5
// 335.947 us; speedup vs baseline: 1.4351x; 1.0438x over previous
//
#include <hip/hip_runtime.h>
#include <hip/hip_bf16.h>

#define DEV __device__ __forceinline__

typedef __attribute__((ext_vector_type(8))) short bf16x8;
typedef __attribute__((ext_vector_type(4))) float f32x4;
typedef unsigned int u32;
typedef unsigned long long u64;

DEV short f2bf(float f) {
  union { float f; u32 u; } x; x.f = f;
  u32 r = x.u + 0x7fffu + ((x.u >> 16) & 1u);   // RNE
  return (short)(r >> 16);
}

DEV void gload_lds16(const void* g, void* l) {
  __builtin_amdgcn_global_load_lds(
      (const __attribute__((address_space(1))) u32*)g,
      (__attribute__((address_space(3))) u32*)l, 16, 0, 0);
}

// Stage a 128-row x 64-short bf16 tile (row stride 2048 B in global) into LDS,
// linear dest, XOR-pre-swizzled source (rule #21: swizzle source + read, dest linear).
DEV void stage_t128(const char* base, int ktb, char* lds, int w, int lane) {
  int r8 = lane >> 3;                       // row within 8-row stripe
  int csw = ((lane & 7) ^ r8) << 4;         // swizzled 16B-chunk column
#pragma unroll
  for (int i = 0; i < 4; ++i) {
    int c = w * 4 + i;
    gload_lds16(base + (size_t)(c * 8 + r8) * 2048 + ktb + csw, lds + c * 1024);
  }
}

// XOR-swizzled fragment read matching stage_t128 layout. col in shorts.
DEV bf16x8 frag(const short* L, int row, int col) {
  return *(const bf16x8*)&L[row * 64 + (col ^ ((row & 7) << 3))];
}

// ---------- activations fp32 -> bf16 (once) ----------
__global__ __launch_bounds__(256) void aconv(const float* __restrict__ q,
    const float* __restrict__ k, const float* __restrict__ v,
    short* __restrict__ qb, short* __restrict__ kb, short* __restrict__ vb) {
  const float* src; short* dst;
  if (blockIdx.z == 0)      { src = q; dst = qb; }
  else if (blockIdx.z == 1) { src = k; dst = kb; }
  else                      { src = v; dst = vb; }
  size_t i = ((size_t)blockIdx.x * 256 + threadIdx.x) * 8;
  float4 f0 = *(const float4*)(src + i);
  float4 f1 = *(const float4*)(src + i + 4);
  bf16x8 o;
  o[0] = f2bf(f0.x); o[1] = f2bf(f0.y); o[2] = f2bf(f0.z); o[3] = f2bf(f0.w);
  o[4] = f2bf(f1.x); o[5] = f2bf(f1.y); o[6] = f2bf(f1.z); o[7] = f2bf(f1.w);
  *(bf16x8*)(dst + i) = o;
}

// ---------- combined mask -> packed bits: pk[b][n][16] u64 ----------
__global__ __launch_bounds__(256) void pack_mask(const int* __restrict__ mask,
                                                 const int* __restrict__ tmask,
                                                 u64* __restrict__ pk) {
  int bn = blockIdx.x;                 // (b*1024 + n)
  int b = bn >> 10;
  int t = threadIdx.x, w = t >> 6, lane = t & 63;
  const int* tr = tmask + (size_t)bn * 1024;
  const int* mr = mask + b * 1024;
#pragma unroll
  for (int it = 0; it < 4; ++it) {
    int m = it * 256 + w * 64 + lane;
    bool on = (mr[m] != 0) && (tr[m] != 0);
    u64 bits = __ballot(on);
    if (lane == 0) pk[(size_t)bn * 16 + it * 4 + w] = bits;
  }
}

// ---------- 4 weights fp32 (K x N) -> bf16 transposed (N x K), fused ----------
__global__ __launch_bounds__(256) void wconv4(const float* __restrict__ W0,
    const float* __restrict__ W1, const float* __restrict__ W2,
    const float* __restrict__ W3, short* __restrict__ WtAll) {
  const float* W = blockIdx.z == 0 ? W0 : blockIdx.z == 1 ? W1
                 : blockIdx.z == 2 ? W2 : W3;
  short* Wt = WtAll + (size_t)blockIdx.z * 1024 * 1024;
  __shared__ short tile[64][65];
  int k0 = blockIdx.x * 64, n0 = blockIdx.y * 64;
  int t = threadIdx.x;
  int r = t >> 2, c = (t & 3) * 16;
  const float* src = W + (size_t)(k0 + r) * 1024 + n0 + c;
#pragma unroll
  for (int i = 0; i < 16; i += 4) {
    float4 f = *(const float4*)(src + i);
    tile[r][c + i + 0] = f2bf(f.x);
    tile[r][c + i + 1] = f2bf(f.y);
    tile[r][c + i + 2] = f2bf(f.z);
    tile[r][c + i + 3] = f2bf(f.w);
  }
  __syncthreads();
  bf16x8 v0, v1;
#pragma unroll
  for (int i = 0; i < 8; ++i) v0[i] = tile[c + i][r];
#pragma unroll
  for (int i = 0; i < 8; ++i) v1[i] = tile[c + 8 + i][r];
  short* dst = Wt + (size_t)(n0 + r) * 1024 + k0 + c;
  *(bf16x8*)(dst) = v0;
  *(bf16x8*)(dst + 8) = v1;
}

// ---------- vh (B,H,M,D) -> vht (B,H,D,M), bf16 ----------
__global__ __launch_bounds__(256) void vtrans(const short* __restrict__ vh,
                                              short* __restrict__ vht) {
  __shared__ short tile[64][65];
  int m0 = blockIdx.x * 64;
  int bh = blockIdx.y;
  int t = threadIdx.x;
  int r = t >> 2, c = (t & 3) * 16;
  const short* src = vh + ((size_t)bh * 1024 + m0 + r) * 64 + c;
  bf16x8 a0 = *(const bf16x8*)(src);
  bf16x8 a1 = *(const bf16x8*)(src + 8);
#pragma unroll
  for (int i = 0; i < 8; ++i) tile[r][c + i] = a0[i];
#pragma unroll
  for (int i = 0; i < 8; ++i) tile[r][c + 8 + i] = a1[i];
  __syncthreads();
  bf16x8 v0, v1;
#pragma unroll
  for (int i = 0; i < 8; ++i) v0[i] = tile[c + i][r];
#pragma unroll
  for (int i = 0; i < 8; ++i) v1[i] = tile[c + 8 + i][r];
  short* dst = vht + ((size_t)bh * 64 + r) * 1024 + m0 + c;
  *(bf16x8*)dst = v0;
  *(bf16x8*)(dst + 8) = v1;
}

// ---------- QKV projection GEMM (all-bf16 operands via gload_lds, swizzled) ----------
// qh is pre-scaled by 0.125*log2(e) so attention can use exp2 directly.
#define QSCALE 0.18033688011112042f

__global__ __launch_bounds__(256, 2) void gemm_qkv(
    const short* __restrict__ qb, const short* __restrict__ kb, const short* __restrict__ vb,
    const short* __restrict__ WtAll,
    short* __restrict__ qh, short* __restrict__ kh, short* __restrict__ vh) {
  // XCD-aware swizzle: 8 n-tiles of one m-panel land contiguously on one XCD.
  int flat = blockIdx.z * 512 + blockIdx.y * 8 + blockIdx.x;
  int nid = (flat & 7) * 192 + (flat >> 3);
  int zz = nid >> 9;
  int rr = nid & 511;
  int bm = (rr >> 3) * 128, bn = (rr & 7) * 128;

  const short* A; short* Ch; float cs;
  if (zz == 0)      { A = qb; Ch = qh; cs = QSCALE; }
  else if (zz == 1) { A = kb; Ch = kh; cs = 1.0f; }
  else              { A = vb; Ch = vh; cs = 1.0f; }
  const short* Wt = WtAll + (size_t)zz * 1024 * 1024;

  __shared__ __align__(16) short As[128 * 64];  // [m][k], XOR-swizzled
  __shared__ __align__(16) short Bs[128 * 64];  // [n][k], XOR-swizzled

  int tid = threadIdx.x;
  int lane = tid & 63, w = tid >> 6;
  int wm = w >> 1, wn = w & 1;
  int lr = lane & 15, lg = lane >> 4;

  const f32x4 fz = {0.f, 0.f, 0.f, 0.f};
  f32x4 acc[4][4];
#pragma unroll
  for (int i = 0; i < 4; ++i)
#pragma unroll
    for (int j = 0; j < 4; ++j) acc[i][j] = fz;

  const char* abase = (const char*)A + (size_t)bm * 2048;
  const char* bbase = (const char*)Wt + (size_t)bn * 2048;

  for (int ktb = 0; ktb < 2048; ktb += 128) {
    stage_t128(abase, ktb, (char*)As, w, lane);
    stage_t128(bbase, ktb, (char*)Bs, w, lane);
    __syncthreads();
#pragma unroll
    for (int ks = 0; ks < 2; ++ks) {
      bf16x8 af[4], bfr[4];
#pragma unroll
      for (int mi = 0; mi < 4; ++mi)
        af[mi] = frag(As, wm * 64 + mi * 16 + lr, ks * 32 + lg * 8);
#pragma unroll
      for (int ni = 0; ni < 4; ++ni)
        bfr[ni] = frag(Bs, wn * 64 + ni * 16 + lr, ks * 32 + lg * 8);
#pragma unroll
      for (int mi = 0; mi < 4; ++mi)
#pragma unroll
        for (int ni = 0; ni < 4; ++ni)
          acc[mi][ni] = __builtin_amdgcn_mfma_f32_16x16x32_bf16(af[mi], bfr[ni], acc[mi][ni], 0, 0, 0);
    }
    __syncthreads();
  }
#pragma unroll
  for (int mi = 0; mi < 4; ++mi)
#pragma unroll
    for (int ni = 0; ni < 4; ++ni) {
      int ccol = bn + wn * 64 + ni * 16 + lr;
      int h = ccol >> 6, d = ccol & 63;
#pragma unroll
      for (int j = 0; j < 4; ++j) {
        int r = bm + wm * 64 + mi * 16 + lg * 4 + j;
        int bb = r >> 10, n = r & 1023;
        Ch[(((size_t)bb * 16 + h) * 1024 + n) * 64 + d] = f2bf(acc[mi][ni][j] * cs);
      }
    }
}

// ---------- flash attention ----------
// 2 q-subtiles (2x128 rows) per block; grid 512 = exactly 2 blocks/CU, no tail.
// K/V staged once per block and reused by both subtiles; separate Ps buffers
// let sub1's QK^T overlap sub0's softmax/PV in the scheduler.
DEV void stage_kv(const char* kbase, const char* vbase, int kv0,
                  short* Ksb, short* Vsb, int w, int lane) {
#pragma unroll
  for (int i = 0; i < 2; ++i) {
    int c = w * 2 + i;
    int row = (lane >> 3);
    int colb = ((lane & 7) ^ row) << 4;          // pre-swizzled source column
    gload_lds16(kbase + (size_t)(kv0 + c * 8 + row) * 128 + colb, (char*)Ksb + c * 1024);
    gload_lds16(vbase + (size_t)(c * 8 + row) * 2048 + kv0 * 2 + colb, (char*)Vsb + c * 1024);
  }
}

__global__ __launch_bounds__(256, 2) void attn(
    const short* __restrict__ qh, const short* __restrict__ kh, const short* __restrict__ vht,
    const u64* __restrict__ pk, short* __restrict__ x) {
  __shared__ __align__(16) short Ks[2][4096];   // [key][d], XOR-swizzled
  __shared__ __align__(16) short Vs[2][4096];   // [d][key], XOR-swizzled
  __shared__ __align__(16) short Ps[2][8192];   // per-subtile [qrow][key], XOR-swizzled

  int flat = blockIdx.y * 8 + blockIdx.x;       // grid (8, 64) = 512 blocks
  int nid = (flat & 7) * 64 + (flat >> 3);      // XCD chunking (bijective: 512 = 8*64)
  int bh = nid >> 2, qp = nid & 3;              // 4 q-pairs (256 rows) per head
  int b = bh >> 4;
  int tid = threadIdx.x, lane = tid & 63, w = tid >> 6;
  int lr = lane & 15, lg = lane >> 4;

  // Q fragments for both subtiles, held in registers
  bf16x8 qa[2][2][2];                           // [sub][mi][ks]
#pragma unroll
  for (int sub = 0; sub < 2; ++sub) {
    const short* qb2 = qh + ((size_t)bh * 1024 + qp * 256 + sub * 128 + w * 32) * 64;
#pragma unroll
    for (int mi = 0; mi < 2; ++mi)
#pragma unroll
      for (int ks = 0; ks < 2; ++ks)
        qa[sub][mi][ks] = *(const bf16x8*)(qb2 + (mi * 16 + lr) * 64 + ks * 32 + lg * 8);
  }

  const f32x4 fz = {0.f, 0.f, 0.f, 0.f};
  f32x4 o[2][2][4];                             // [sub][mi][nd]
  float psum[2][2][4];
#pragma unroll
  for (int sub = 0; sub < 2; ++sub)
#pragma unroll
    for (int mi = 0; mi < 2; ++mi)
#pragma unroll
      for (int j = 0; j < 4; ++j) { psum[sub][mi][j] = 0.f; o[sub][mi][j] = fz; }

  const char* kbase = (const char*)(kh + (size_t)bh * 65536);
  const char* vbase = (const char*)(vht + (size_t)bh * 65536);
  const u64* pkb = pk + ((size_t)b * 1024 + qp * 256) * 16;

  stage_kv(kbase, vbase, 0, Ks[0], Vs[0], w, lane);
  __syncthreads();
  int cur = 0;

  for (int t = 0; t < 16; ++t) {
    if (t < 15) stage_kv(kbase, vbase, (t + 1) * 64, Ks[cur ^ 1], Vs[cur ^ 1], w, lane);

#pragma unroll
    for (int sub = 0; sub < 2; ++sub) {
      // packed mask words (L2-resident broadcast loads)
      u64 pw[2][4];
#pragma unroll
      for (int mi = 0; mi < 2; ++mi)
#pragma unroll
        for (int j = 0; j < 4; ++j)
          pw[mi][j] = pkb[(sub * 128 + w * 32 + mi * 16 + lg * 4 + j) * 16 + t];

      // S = Q K^T  (qh pre-scaled by 0.125*log2e)
      f32x4 s[2][4];
#pragma unroll
      for (int mi = 0; mi < 2; ++mi)
#pragma unroll
        for (int ni = 0; ni < 4; ++ni) s[mi][ni] = fz;
      __builtin_amdgcn_s_setprio(1);
#pragma unroll
      for (int ks = 0; ks < 2; ++ks) {
        bf16x8 kb2[4];
#pragma unroll
        for (int ni = 0; ni < 4; ++ni)
          kb2[ni] = *(const bf16x8*)&Ks[cur][(ni * 16 + lr) * 64 + ((ks * 32 + lg * 8) ^ ((lr & 7) << 3))];
#pragma unroll
        for (int mi = 0; mi < 2; ++mi)
#pragma unroll
          for (int ni = 0; ni < 4; ++ni)
            s[mi][ni] = __builtin_amdgcn_mfma_f32_16x16x32_bf16(qa[sub][mi][ks], kb2[ni], s[mi][ni], 0, 0, 0);
      }
      __builtin_amdgcn_s_setprio(0);

      // P = mask ? exp2(S) : 0 ; psum accumulate; P -> LDS (bf16, 2-op round)
#pragma unroll
      for (int mi = 0; mi < 2; ++mi)
#pragma unroll
        for (int j = 0; j < 4; ++j) {
          u32 lo = (u32)pw[mi][j], hi = (u32)(pw[mi][j] >> 32);
          int r = w * 32 + mi * 16 + lg * 4 + j;
          int sw = (r & 7) << 3;
          float rs = 0.f;
#pragma unroll
          for (int ni = 0; ni < 4; ++ni) {
            u32 bit = ((ni < 2 ? lo : hi) >> ((ni & 1) * 16 + lr)) & 1u;
            float e = __builtin_amdgcn_exp2f(s[mi][ni][j]);
            float p = bit ? e : 0.f;
            rs += p;
            union { float f; u32 u; } cv; cv.f = p;
            Ps[sub][r * 64 + ((ni * 16 + lr) ^ sw)] = (short)((cv.u + 0x8000u) >> 16);
          }
          psum[sub][mi][j] += rs;
        }

      // O += P V
      __builtin_amdgcn_s_setprio(1);
#pragma unroll
      for (int ks = 0; ks < 2; ++ks) {
        bf16x8 pa[2], vb2[4];
#pragma unroll
        for (int mi = 0; mi < 2; ++mi)
          pa[mi] = *(const bf16x8*)&Ps[sub][(w * 32 + mi * 16 + lr) * 64 + ((ks * 32 + lg * 8) ^ ((lr & 7) << 3))];
#pragma unroll
        for (int nd = 0; nd < 4; ++nd)
          vb2[nd] = *(const bf16x8*)&Vs[cur][(nd * 16 + lr) * 64 + ((ks * 32 + lg * 8) ^ ((lr & 7) << 3))];
#pragma unroll
        for (int mi = 0; mi < 2; ++mi)
#pragma unroll
          for (int nd = 0; nd < 4; ++nd)
            o[sub][mi][nd] = __builtin_amdgcn_mfma_f32_16x16x32_bf16(pa[mi], vb2[nd], o[sub][mi][nd], 0, 0, 0);
      }
      __builtin_amdgcn_s_setprio(0);
    }
    __syncthreads();
    cur ^= 1;
  }

  // epilogue: one sum-reduction tree per row, then normalize + store
  short* xb = x + ((size_t)b * 1024) * 1024 + (bh & 15) * 64;
#pragma unroll
  for (int sub = 0; sub < 2; ++sub)
#pragma unroll
    for (int mi = 0; mi < 2; ++mi)
#pragma unroll
      for (int j = 0; j < 4; ++j) {
        float rs = psum[sub][mi][j];
#pragma unroll
        for (int dd = 1; dd < 16; dd <<= 1) rs += __shfl_xor(rs, dd, 64);
        float inv = rs > 0.f ? 1.0f / rs : 0.f;
        int qg = qp * 256 + sub * 128 + w * 32 + mi * 16 + lg * 4 + j;
#pragma unroll
        for (int nd = 0; nd < 4; ++nd) {
          int d = nd * 16 + lr;
          xb[(size_t)qg * 1024 + d] = f2bf(o[sub][mi][nd][j] * inv);
        }
      }
}

// ---------- output GEMM: x(8192x1024 bf16) @ Wot^T + bo -> fp32 ----------
__global__ __launch_bounds__(256, 2) void gemm_out(
    const short* __restrict__ X, const short* __restrict__ Wot,
    const float* __restrict__ bo, float* __restrict__ out) {
  int flat = blockIdx.y * 8 + blockIdx.x;       // grid (8 n, 64 m)
  int nid = (flat & 7) * 64 + (flat >> 3);
  int bm = (nid >> 3) * 128, bn = (nid & 7) * 128;

  __shared__ __align__(16) short As[128 * 64];
  __shared__ __align__(16) short Bs[128 * 64];
  int tid = threadIdx.x, lane = tid & 63, w = tid >> 6;
  int wm = w >> 1, wn = w & 1, lr = lane & 15, lg = lane >> 4;

  const f32x4 fz = {0.f, 0.f, 0.f, 0.f};
  f32x4 acc[4][4];
#pragma unroll
  for (int i = 0; i < 4; ++i)
#pragma unroll
    for (int j = 0; j < 4; ++j) acc[i][j] = fz;

  const char* abase = (const char*)X + (size_t)bm * 2048;
  const char* bbase = (const char*)Wot + (size_t)bn * 2048;

  for (int ktb = 0; ktb < 2048; ktb += 128) {
    stage_t128(abase, ktb, (char*)As, w, lane);
    stage_t128(bbase, ktb, (char*)Bs, w, lane);
    __syncthreads();
#pragma unroll
    for (int ks = 0; ks < 2; ++ks) {
      bf16x8 af[4], bfr[4];
#pragma unroll
      for (int mi = 0; mi < 4; ++mi)
        af[mi] = frag(As, wm * 64 + mi * 16 + lr, ks * 32 + lg * 8);
#pragma unroll
      for (int ni = 0; ni < 4; ++ni)
        bfr[ni] = frag(Bs, wn * 64 + ni * 16 + lr, ks * 32 + lg * 8);
#pragma unroll
      for (int mi = 0; mi < 4; ++mi)
#pragma unroll
        for (int ni = 0; ni < 4; ++ni)
          acc[mi][ni] = __builtin_amdgcn_mfma_f32_16x16x32_bf16(af[mi], bfr[ni], acc[mi][ni], 0, 0, 0);
    }
    __syncthreads();
  }
#pragma unroll
  for (int mi = 0; mi < 4; ++mi)
#pragma unroll
    for (int ni = 0; ni < 4; ++ni) {
      int ccol = bn + wn * 64 + ni * 16 + lr;
      float bias = bo[ccol];
#pragma unroll
      for (int j = 0; j < 4; ++j) {
        int r = bm + wm * 64 + mi * 16 + lg * 4 + j;
        out[(size_t)r * 1024 + ccol] = acc[mi][ni][j] + bias;
      }
    }
}

extern "C" void kernel_launch(void* const* d_in, const int* in_sizes, int n_in,
                              void* d_out, int out_size, void* d_ws, size_t ws_size,
                              hipStream_t stream) {
  const float* q = (const float*)d_in[0];
  const float* k = (const float*)d_in[1];
  const float* v = (const float*)d_in[2];
  const int* mask = (const int*)d_in[3];
  const int* tmask = (const int*)d_in[4];
  const float* Wq = (const float*)d_in[5];
  const float* Wk = (const float*)d_in[6];
  const float* Wv = (const float*)d_in[7];
  const float* Wo = (const float*)d_in[8];
  const float* bo = (const float*)d_in[9];
  float* out = (float*)d_out;

  char* ws = (char*)d_ws;
  const size_t MB = 1u << 20;
  if (ws_size < 73 * MB) return;
  short* WtAll = (short*)(ws + 0 * MB);   // Wqt,Wkt,Wvt,Wot contiguous (8 MB)
  short* qh  = (short*)(ws + 8 * MB);
  short* kh  = (short*)(ws + 24 * MB);
  short* vh  = (short*)(ws + 40 * MB);
  short* vht = (short*)(ws + 56 * MB);
  u64*   pkb = (u64*)(ws + 72 * MB);      // 1 MB packed masks
  short* x   = (short*)(ws + 40 * MB);    // aliases vh (dead after vtrans)
  // qb/kb live in d_out (32 MB, overwritten by gemm_out at the very end);
  // vb aliases the vht region (vht written only later, by vtrans).
  short* qbA = (short*)d_out;
  short* kbA = (short*)d_out + 8 * 1024 * 1024;
  short* vbA = (short*)(ws + 56 * MB);

  aconv<<<dim3(4096, 1, 3), 256, 0, stream>>>(q, k, v, qbA, kbA, vbA);
  wconv4<<<dim3(16, 16, 4), 256, 0, stream>>>(Wq, Wk, Wv, Wo, WtAll);
  pack_mask<<<dim3(8192), 256, 0, stream>>>(mask, tmask, pkb);

  gemm_qkv<<<dim3(8, 64, 3), 256, 0, stream>>>(qbA, kbA, vbA, WtAll, qh, kh, vh);
  vtrans<<<dim3(16, 128), 256, 0, stream>>>(vh, vht);
  attn<<<dim3(8, 64), 256, 0, stream>>>(qh, kh, vht, pkb, x);
  gemm_out<<<dim3(8, 64), 256, 0, stream>>>(x, WtAll + 3 * 1024 * 1024, bo, out);
}